// Round 11
// baseline (354.882 us; speedup 1.0000x reference)
//
#include <hip/hip_runtime.h>
#include <stdint.h>

#define BATCH 4
#define CH 64
#define NPT 100000
#define NY 496
#define NX 432
#define NYNX (NY * NX)
// XLA folds x/0.16f into x * 6.25f; match bit-for-bit.
#define INV_PILLAR 6.25f

// native clang vector types (HIP float4 is a class; nontemporal builtin rejects it)
typedef float vfloat4 __attribute__((ext_vector_type(4)));

// ws layout
#define MINBITS_OFF 0                         // 8 uints (256 B reserved)
#define WINNER_OFF  256                       // B*NY*NX ints
#define WINNER_BYTES ((size_t)BATCH * NYNX * sizeof(int))
#define FEATT_OFF   ((WINNER_OFF + WINNER_BYTES + 255) & ~(size_t)255)
#define FEATT_BYTES ((size_t)BATCH * (NPT + 1) * CH * sizeof(unsigned short))
#define WS_NEEDED   (FEATT_OFF + FEATT_BYTES)

// monotone float<->uint encoding for atomic min
__device__ __forceinline__ unsigned int f2sortable(float f) {
    unsigned int u = __float_as_uint(f);
    return (u & 0x80000000u) ? ~u : (u | 0x80000000u);
}
__device__ __forceinline__ float sortable2f(unsigned int u) {
    unsigned int b = (u & 0x80000000u) ? (u ^ 0x80000000u) : ~u;
    return __uint_as_float(b);
}
// f32 -> bf16 round-to-nearest-even (inputs finite)
__device__ __forceinline__ unsigned short f2bf(float f) {
    unsigned int u = __float_as_uint(f);
    unsigned int r = u + 0x7FFFu + ((u >> 16) & 1u);
    return (unsigned short)(r >> 16);
}

#define CHUNKS_PER_BATCH 64
#define PTS_PER_CHUNK ((NPT + CHUNKS_PER_BATCH - 1) / CHUNKS_PER_BATCH)

__global__ void minred_kernel(const float* __restrict__ points,
                              unsigned int* __restrict__ minbits) {
    int b = blockIdx.x / CHUNKS_PER_BATCH;
    int chunk = blockIdx.x % CHUNKS_PER_BATCH;
    int lo = chunk * PTS_PER_CHUNK;
    int hi = min(lo + PTS_PER_CHUNK, NPT);
    const vfloat4* pts = (const vfloat4*)points + (size_t)b * NPT;
    float mx = 3.0e38f, my = 3.0e38f;
    for (int i = lo + threadIdx.x; i < hi; i += blockDim.x) {
        vfloat4 p = pts[i];          // (bidx, x, y, z) — cached; winner re-reads
        mx = fminf(mx, p.y);
        my = fminf(my, p.z);
    }
    #pragma unroll
    for (int off = 32; off; off >>= 1) {
        mx = fminf(mx, __shfl_xor(mx, off));
        my = fminf(my, __shfl_xor(my, off));
    }
    if ((threadIdx.x & 63) == 0) {
        atomicMin(&minbits[2 * b],     f2sortable(mx));
        atomicMin(&minbits[2 * b + 1], f2sortable(my));
    }
}

__global__ void winner_kernel(const float* __restrict__ points,
                              const unsigned int* __restrict__ minbits,
                              int* __restrict__ winner) {
    int i = blockIdx.x * blockDim.x + threadIdx.x;
    if (i >= BATCH * NPT) return;
    int b = i / NPT;
    int li = i - b * NPT;
    vfloat4 p = ((const vfloat4*)points)[i];
    float xmin = sortable2f(minbits[2 * b]);
    float ymin = sortable2f(minbits[2 * b + 1]);
    float fx = fminf(fmaxf(floorf((p.y - xmin) * INV_PILLAR), 0.0f), (float)(NX - 1));
    float fy = fminf(fmaxf(floorf((p.z - ymin) * INV_PILLAR), 0.0f), (float)(NY - 1));
    int xi = (int)fx;
    int yi = (int)fy;
    // last-write-wins: store li+1; winner initialized to -1 (0xFF fill)
    atomicMax(&winner[(b * NY + yi) * NX + xi], li + 1);
}

// Transpose feat (B, C, N) f32 -> feat_t (B, N+1, C) bf16; row N = zero
// sentinel. One block per 64(C) x 64(N) tile.
#define NTILES ((NPT + 1 + 63) / 64)
__global__ void transpose_kernel(const float* __restrict__ feat,
                                 unsigned short* __restrict__ feat_t) {
    __shared__ float tile[CH][65];   // 65 ≡ 1 (mod 32): row-step = 1 bank
    int b = blockIdx.x / NTILES;
    int n0 = (blockIdx.x % NTILES) * 64;
    int t = threadIdx.x;

    // load: thread (l16 = t%16, crow = t/16): feat[b][crow+16k][n0+4*l16 ..+3]
    // banks: (c + 4*l16 + j) % 32 -> <=2 lanes/bank (free)
    int l16 = t & 15;
    int crow = t >> 4;
    int nt4 = l16 * 4;
    if (n0 + nt4 + 3 < NPT) {
        #pragma unroll
        for (int k = 0; k < 4; ++k) {
            int c = crow + 16 * k;
            vfloat4 v = __builtin_nontemporal_load(
                (const vfloat4*)(feat + ((size_t)b * CH + c) * NPT + n0 + nt4));
            tile[c][nt4 + 0] = v.x;
            tile[c][nt4 + 1] = v.y;
            tile[c][nt4 + 2] = v.z;
            tile[c][nt4 + 3] = v.w;
        }
    } else {
        #pragma unroll
        for (int k = 0; k < 4; ++k) {
            int c = crow + 16 * k;
            for (int j = 0; j < 4; ++j) {
                int n = n0 + nt4 + j;
                tile[c][nt4 + j] = (n < NPT) ? feat[((size_t)b * CH + c) * NPT + n] : 0.0f;
            }
        }
    }
    __syncthreads();

    // store: thread (c8 = (t&7)*8, nr = t>>3): feat_t[b][n0+nr+32k][c8..c8+7]
    // as uint4 (16 B/thread, 1 KB contiguous per wave).
    // LDS read banks: (c8 + j + nr) % 32 -> exactly 2 lanes/bank (free)
    int c8 = (t & 7) * 8;
    int nr = t >> 3;
    #pragma unroll
    for (int k = 0; k < 2; ++k) {
        int nit = nr + 32 * k;
        int n = n0 + nit;
        if (n < NPT) {
            unsigned int w0 = (unsigned int)f2bf(tile[c8 + 0][nit]) |
                              ((unsigned int)f2bf(tile[c8 + 1][nit]) << 16);
            unsigned int w1 = (unsigned int)f2bf(tile[c8 + 2][nit]) |
                              ((unsigned int)f2bf(tile[c8 + 3][nit]) << 16);
            unsigned int w2 = (unsigned int)f2bf(tile[c8 + 4][nit]) |
                              ((unsigned int)f2bf(tile[c8 + 5][nit]) << 16);
            unsigned int w3 = (unsigned int)f2bf(tile[c8 + 6][nit]) |
                              ((unsigned int)f2bf(tile[c8 + 7][nit]) << 16);
            *(uint4*)(feat_t + ((size_t)b * (NPT + 1) + n) * CH + c8) =
                make_uint4(w0, w1, w2, w3);
        } else if (n == NPT) {
            *(uint4*)(feat_t + ((size_t)b * (NPT + 1) + n) * CH + c8) =
                make_uint4(0u, 0u, 0u, 0u);
        }
    }
}

// 4 cells per thread: int4 winner read, 32 16B gathers, 64 float4 NT stores.
#define QUADS_PER_BATCH (NYNX / 4)     // 53568
__global__ void scatter_kernel(const unsigned short* __restrict__ feat_t,
                               const int* __restrict__ winner,
                               float* __restrict__ out) {
    int s = blockIdx.x * blockDim.x + threadIdx.x;   // quad id
    if (s >= BATCH * QUADS_PER_BATCH) return;
    int b = s / QUADS_PER_BATCH;
    int yx0 = (s - b * QUADS_PER_BATCH) * 4;
    int4 w4 = *(const int4*)(winner + (size_t)b * NYNX + yx0);
    const unsigned short* fb = feat_t + (size_t)b * (NPT + 1) * CH;
    int wv[4] = {w4.x, w4.y, w4.z, w4.w};
    const uint4* col[4];
    #pragma unroll
    for (int i = 0; i < 4; ++i) {
        int c = (wv[i] < 0) ? NPT : (wv[i] - 1);   // sentinel row = zeros
        col[i] = (const uint4*)(fb + (size_t)c * CH);
    }
    float* ob = out + (size_t)b * CH * NYNX + yx0;
    #pragma unroll
    for (int g = 0; g < 4; ++g) {                  // 16 channels per group
        uint4 ua[4], ub[4];
        #pragma unroll
        for (int i = 0; i < 4; ++i) {
            ua[i] = col[i][2 * g];
            ub[i] = col[i][2 * g + 1];
        }
        #pragma unroll
        for (int c = 0; c < 16; ++c) {
            int pair = c >> 1;
            vfloat4 v;
            #pragma unroll
            for (int i = 0; i < 4; ++i) {
                unsigned int src = (pair < 4) ? (&ua[i].x)[pair] : (&ub[i].x)[pair - 4];
                v[i] = __uint_as_float((c & 1) ? (src & 0xFFFF0000u) : (src << 16));
            }
            __builtin_nontemporal_store(
                v, (vfloat4*)(ob + (size_t)(16 * g + c) * NYNX));
        }
    }
}

// Fallback scatter (direct strided gather, f32) if ws is too small.
__global__ void scatter_fallback_kernel(const float* __restrict__ feat,
                                        const int* __restrict__ winner,
                                        float* __restrict__ out) {
    int cell = blockIdx.x * blockDim.x + threadIdx.x;
    if (cell >= BATCH * NYNX) return;
    int b = cell / NYNX;
    int yx = cell - b * NYNX;
    int w = winner[cell];
    int ws_ = (w > 0) ? (w - 1) : 0;
    const float* fb = feat + (size_t)b * CH * NPT;
    float* ob = out + (size_t)b * CH * NYNX + yx;
    #pragma unroll 16
    for (int c = 0; c < CH; ++c) {
        float v = fb[(size_t)c * NPT + ws_];
        ob[(size_t)c * NYNX] = (w > 0) ? v : 0.0f;
    }
}

extern "C" void kernel_launch(void* const* d_in, const int* in_sizes, int n_in,
                              void* d_out, int out_size, void* d_ws, size_t ws_size,
                              hipStream_t stream) {
    const float* point_feature = (const float*)d_in[0];  // (B, C, N) f32
    const float* points        = (const float*)d_in[1];  // (B*N, 4) f32
    float* out = (float*)d_out;                          // (B, C, NY, NX) f32

    unsigned int*   minbits = (unsigned int*)((char*)d_ws + MINBITS_OFF);
    int*            winner  = (int*)((char*)d_ws + WINNER_OFF);
    unsigned short* feat_t  = (unsigned short*)((char*)d_ws + FEATT_OFF);

    // one fill: minbits -> 0xFFFFFFFF (+inf sortable), winner -> -1 (empty)
    (void)hipMemsetAsync(d_ws, 0xFF, WINNER_OFF + WINNER_BYTES, stream);

    minred_kernel<<<BATCH * CHUNKS_PER_BATCH, 256, 0, stream>>>(points, minbits);

    int npts = BATCH * NPT;
    winner_kernel<<<(npts + 255) / 256, 256, 0, stream>>>(points, minbits, winner);

    if (ws_size >= WS_NEEDED) {
        transpose_kernel<<<BATCH * NTILES, 256, 0, stream>>>(point_feature, feat_t);
        int nquad = BATCH * QUADS_PER_BATCH;
        scatter_kernel<<<(nquad + 255) / 256, 256, 0, stream>>>(feat_t, winner, out);
    } else {
        int ncell = BATCH * NYNX;
        scatter_fallback_kernel<<<(ncell + 255) / 256, 256, 0, stream>>>(
            point_feature, winner, out);
    }
}